// Round 3
// baseline (481.188 us; speedup 1.0000x reference)
//
#include <hip/hip_runtime.h>
#include <math.h>

typedef unsigned short ushort_t;
typedef unsigned short u16x8 __attribute__((ext_vector_type(8)));
typedef unsigned short u16x4 __attribute__((ext_vector_type(4)));
typedef float f32x4 __attribute__((ext_vector_type(4)));

#define THREADS 512
#define E_TILE  64
#define NBASIS  512
#define NBF     128
#define SBD     16
#define MBD     9
#define NTAP    17
#define XE_S    136   // ushort stride (128 + 8 pad)
#define H_S     40    // ushort stride (32 + 8 pad)

// d_ws layout (ushort bf16)
#define WS_WET   0        // W_edge^T  [n=128][k=128]
#define WS_WG1T  16384    // W_g1^T    [q=32][k=128]
#define WS_WG2T  20480    // W_g2^T    [b*128+n=640][k=32]
#define WS_TOTAL 40960

// LDS offsets (float units)  -- total 9408 floats = 36.75 KB
#define OFF_XS  0      // 64*16
#define OFF_SH  1024   // 64*16
#define OFF_G   2048   // 64*17 (dead after P1)
#define OFF_JLO 3136   // 64 int (dead after P1)
#define OFF_SRC 3200   // 64 int (dead after P1)
#define OFF_TGT 3264   // 64 int (dead after P1)
#define OFF_HS  2048   // aliases G..TGT: 1280 floats = 64*40 ushort (h, written P3)
#define OFF_TPA 3328   // 64*16
#define OFF_TPM 4352   // 64*10 (stride 10)
#define OFF_SUM 4992   // 64
#define OFF_XE  5056   // 4352 floats = 64*136 ushort (xe1, then xe2)
#define SMEM_FLOATS 9408

__device__ __forceinline__ float fsigmoid(float x){ return 1.0f/(1.0f + __expf(-x)); }
__device__ __forceinline__ float fsilu(float x){ return x/(1.0f + __expf(-x)); }

__device__ __forceinline__ ushort_t f2bf(float f){
  unsigned int u = __float_as_uint(f);
  u += 0x7FFFu + ((u >> 16) & 1u);
  return (ushort_t)(u >> 16);
}
__device__ __forceinline__ float bf2f(ushort_t h){
  return __uint_as_float(((unsigned int)h) << 16);
}
__device__ __forceinline__ void mfma_bf16(f32x4& d, u16x8 a, u16x8 b){
  // D[m][n] += A[m][k]*B[k][n]; A-frag lane(l): m=l&15, k=(l>>4)*8+j; B-frag lane(l): n=l&15, k=(l>>4)*8+j
  asm volatile("v_mfma_f32_16x16x32_bf16 %0, %1, %2, %0" : "+v"(d) : "v"(a), "v"(b));
}

__global__ void prep_weights_kernel(const float* __restrict__ We,
                                    const float* __restrict__ Wg1,
                                    const float* __restrict__ Wg2,
                                    ushort_t* __restrict__ ws){
  int tid = blockIdx.x * 256 + threadIdx.x;
  if (tid < 16384) {                       // WeT[n][k] = We[k][n]
    int n = tid >> 7, k = tid & 127;
    ws[WS_WET + tid] = f2bf(We[k*128 + n]);
  } else if (tid < 20480) {                // Wg1T[q][k] = Wg1[k][q]
    int r = tid - 16384; int q = r >> 7, k = r & 127;
    ws[tid] = f2bf(Wg1[k*32 + q]);
  } else if (tid < WS_TOTAL) {             // Wg2T[b*128+n][k] = Wg2[k][b*128+n]
    int r = tid - 20480; int bn = r >> 5, k = r & 31;
    ws[tid] = f2bf(Wg2[k*640 + bn]);
  }
}

__global__ __launch_bounds__(THREADS, 6)
void edge_block_kernel(
    const float* __restrict__ edge_distance,
    const int*   __restrict__ source_element,
    const int*   __restrict__ target_element,
    const float* __restrict__ x_sph,
    const float* __restrict__ edge_sh,
    const float* __restrict__ W_dist,
    const float* __restrict__ b_dist,
    const float* __restrict__ src_emb,
    const float* __restrict__ tgt_emb,
    const float* __restrict__ b_edge,
    const float* __restrict__ b_g1,
    const float* __restrict__ b_g2,
    const float* __restrict__ cg_mid,
    const float* __restrict__ cg_all,
    const float* __restrict__ W_path,
    const ushort_t* __restrict__ wT,
    float* __restrict__ out,
    int E)
{
  __shared__ float smem[SMEM_FLOATS];
  float* xs_s  = smem + OFF_XS;
  float* sh_s  = smem + OFF_SH;
  float* g_s   = smem + OFF_G;
  int*   jlo_s = (int*)(smem + OFF_JLO);
  int*   src_s = (int*)(smem + OFF_SRC);
  int*   tgt_s = (int*)(smem + OFF_TGT);
  float* tpa_s = smem + OFF_TPA;
  float* tpm_s = smem + OFF_TPM;
  float* sum_s = smem + OFF_SUM;
  ushort_t* xe = (ushort_t*)(smem + OFF_XE);
  ushort_t* hS = (ushort_t*)(smem + OFF_HS);   // aliases g/jlo/src/tgt (dead after P1)

  const int tid  = threadIdx.x;
  const int lane = tid & 63;
  const int wid  = tid >> 6;       // 0..7
  const int l16  = lane & 15;
  const int lq   = lane >> 4;      // 0..3
  const int eb   = blockIdx.x * E_TILE;
  const int ne   = min(E_TILE, E - eb);

  // ---------------- P0: stage inputs ----------------
  for (int idx = tid; idx < E_TILE*SBD; idx += THREADS) {
    int e = idx >> 4;
    bool v = (e < ne);
    int gidx = (eb + e)*SBD + (idx & 15);
    xs_s[idx] = v ? x_sph[gidx]   : 0.0f;
    sh_s[idx] = v ? edge_sh[gidx] : 0.0f;
  }
  if (tid < E_TILE) {
    bool v = (tid < ne);
    int ge = eb + tid;
    src_s[tid] = v ? source_element[ge] : 0;
    tgt_s[tid] = v ? target_element[ge] : 0;
  }
  const float INVD = (float)(NBASIS - 1) / 6.0f;   // 511/6
  for (int idx = tid; idx < E_TILE*NTAP; idx += THREADS) {
    int e = idx / NTAP;
    int t = idx - e*NTAP;
    bool v = (e < ne);
    float d  = v ? edge_distance[eb + e] : 0.0f;
    float jd = d * INVD;
    int jlo  = (int)floorf(jd) - 8;
    int j    = jlo + t;
    float dj = jd - (float)j;
    float g  = (v && j >= 0 && j < NBASIS) ? __expf(-0.5f*dj*dj) : 0.0f;
    g_s[e*NTAP + t] = g;
    if (t == 0) jlo_s[e] = jlo;
  }
  __syncthreads();

  // ---------------- P1: x_dist (17 taps) + emb + silu -> xe1 bf16 ------
  {
    const int er = tid >> 5;       // 0..15 -> 4 edges each
    const int cq = tid & 31;       // 0..31 -> 4 channels each
    const int e0 = er << 2;
    const int c0 = cq << 2;
    float acc[4][4];
    const float4 bd = *(const float4*)(b_dist + c0);
    #pragma unroll
    for (int i=0;i<4;i++){ acc[i][0]=bd.x; acc[i][1]=bd.y; acc[i][2]=bd.z; acc[i][3]=bd.w; }
    for (int t=0; t<NTAP; t++){
      #pragma unroll
      for (int i=0;i<4;i++){
        int e = e0 + i;
        float g = g_s[e*NTAP + t];
        int j = jlo_s[e] + t;
        j = max(0, min(NBASIS-1, j));
        const float4 w = *(const float4*)(W_dist + j*NBF + c0);
        acc[i][0] += g*w.x; acc[i][1] += g*w.y; acc[i][2] += g*w.z; acc[i][3] += g*w.w;
      }
    }
    #pragma unroll
    for (int i=0;i<4;i++){
      int e = e0 + i;
      const float4 se = *(const float4*)(src_emb + src_s[e]*NBF + c0);
      const float4 te = *(const float4*)(tgt_emb + tgt_s[e]*NBF + c0);
      u16x4 v;
      v[0] = f2bf(fsilu(acc[i][0] + se.x + te.x));
      v[1] = f2bf(fsilu(acc[i][1] + se.y + te.y));
      v[2] = f2bf(fsilu(acc[i][2] + se.z + te.z));
      v[3] = f2bf(fsilu(acc[i][3] + se.w + te.w));
      *(u16x4*)(xe + e*XE_S + c0) = v;
    }
  }

  // ---------------- P4: tensor products (VALU, cg from global/L1) ------
  {
    const int kk = tid & 31;       // output idx: 0..8 mid, 9..24 all
    const int eg = tid >> 5;       // 4 edges
    if (kk < 25) {
      float shv[4][16];
      #pragma unroll
      for (int ii=0; ii<4; ii++)
        #pragma unroll
        for (int j=0;j<16;j++)
          shv[ii][j] = sh_s[(eg*4+ii)*SBD + j];
      float accT[4] = {0.f,0.f,0.f,0.f};
      const bool mid = (kk < 9);
      const float* cgb = mid ? (cg_mid + kk) : (cg_all + (kk-9));
      const int cgs = mid ? MBD : SBD;
      for (int i=0;i<SBD;i++){
        float cgv[16];
        #pragma unroll
        for (int j=0;j<16;j++) cgv[j] = cgb[(i*16+j)*cgs];
        #pragma unroll
        for (int e=0;e<4;e++){
          float s = 0.0f;
          #pragma unroll
          for (int j=0;j<16;j++) s += shv[e][j]*cgv[j];
          accT[e] += xs_s[(eg*4+e)*SBD + i] * s;
        }
      }
      if (mid) {
        #pragma unroll
        for (int e=0;e<4;e++) tpm_s[(eg*4+e)*10 + kk] = accT[e];
      } else {
        #pragma unroll
        for (int e=0;e<4;e++) tpa_s[(eg*4+e)*SBD + (kk-9)] = accT[e];
      }
    }
  }
  __syncthreads();   // publishes xe1, tpa, tpm

  // ---------------- P2: xe2 = silu(xe1 @ W_edge + b_edge) via MFMA -----
  const int m0 = (wid & 3) * 16;
  const int nb = (wid >> 2) * 64;
  {
    f32x4 acc2[4];
    #pragma unroll
    for (int t=0;t<4;t++) acc2[t] = (f32x4){0.f,0.f,0.f,0.f};
    #pragma unroll
    for (int kk=0; kk<4; kk++){
      const u16x8 a = *(const u16x8*)(xe + (m0 + l16)*XE_S + kk*32 + lq*8);
      #pragma unroll
      for (int t=0;t<4;t++){
        const u16x8 b = *(const u16x8*)(wT + WS_WET + (nb + t*16 + l16)*128 + kk*32 + lq*8);
        mfma_bf16(acc2[t], a, b);
      }
    }
    __syncthreads();   // all xe1 reads done -> safe to overwrite with xe2
    #pragma unroll
    for (int t=0;t<4;t++){
      const int n = nb + t*16 + l16;
      const float be = b_edge[n];
      #pragma unroll
      for (int j=0;j<4;j++){
        const int m = m0 + lq*4 + j;
        xe[m*XE_S + n] = f2bf(fsilu(acc2[t][j] + be));
      }
    }
  }
  if (tid < E_TILE) {   // tp_all_g row-sum (tpa published at previous barrier)
    float ta0 = tpa_s[tid*SBD];
    float ss = 0.0f;
    #pragma unroll
    for (int k=1;k<16;k++) ss += tpa_s[tid*SBD + k];
    float sg = fsigmoid(ta0);
    sum_s[tid] = ta0*sg + sg*ss;
  }
  __syncthreads();   // publishes xe2, sum_s

  // ---------------- P3: h = relu(xe2 @ W_g1 + b_g1) via MFMA -----------
  {
    const int n0 = (wid >> 2) * 16;   // 0 or 16
    f32x4 acc3 = (f32x4){0.f,0.f,0.f,0.f};
    #pragma unroll
    for (int kk=0; kk<4; kk++){
      const u16x8 a = *(const u16x8*)(xe + (m0 + l16)*XE_S + kk*32 + lq*8);
      const u16x8 b = *(const u16x8*)(wT + WS_WG1T + (n0 + l16)*128 + kk*32 + lq*8);
      mfma_bf16(acc3, a, b);
    }
    const float bg = b_g1[n0 + l16];
    #pragma unroll
    for (int j=0;j<4;j++){
      const int m = m0 + lq*4 + j;
      hS[m*H_S + n0 + l16] = f2bf(fmaxf(acc3[j] + bg, 0.0f));
    }
  }
  __syncthreads();   // publishes h

  // ------- P5+P6 merged: per 16-ch tile t: gate MFMA x5, softmax, store
  {
    const int cb = (wid >> 2) * 64;
    const u16x8 ah = *(const u16x8*)(hS + (m0 + l16)*H_S + lq*8);
    #pragma unroll
    for (int t=0;t<4;t++){
      const int c = cb + t*16 + l16;
      float sden4[4] = {0.f,0.f,0.f,0.f};
      float z0e4[4];
      #pragma unroll
      for (int b=0;b<5;b++){
        const u16x8 bw = *(const u16x8*)(wT + WS_WG2T + (b*128 + c)*32 + lq*8);
        f32x4 z = (f32x4){0.f,0.f,0.f,0.f};
        mfma_bf16(z, ah, bw);
        const float bg = b_g2[b*128 + c];
        #pragma unroll
        for (int j=0;j<4;j++){
          float ez = __expf(z[j] + bg);
          sden4[j] += ez;
          if (b == 0) z0e4[j] = ez;
        }
      }
      const float wp0 = W_path[c];
      const float wp1 = W_path[128 + c];
      const float wp2 = W_path[256 + c];
      #pragma unroll
      for (int j=0;j<4;j++){
        const int m = m0 + lq*4 + j;
        if (m < ne){
          const float sa = sum_s[m];
          const float g0 = z0e4[j] / sden4[j];
          const float base = bf2f(xe[m*XE_S + c]) + sa;
          const float s0 = tpm_s[m*10] * wp0;
          const float sg = fsigmoid(s0);
          const float gg = sg * g0;
          float* op = out + (size_t)(eb + m) * (MBD*NBF);
          op[c] = s0*gg + base;
          #pragma unroll
          for (int k=1;k<MBD;k++){
            const float w = (k < 4) ? wp1 : wp2;
            op[k*NBF + c] = tpm_s[m*10 + k]*w*gg + base;
          }
        }
      }
    }
  }
}

extern "C" void kernel_launch(void* const* d_in, const int* in_sizes, int n_in,
                              void* d_out, int out_size, void* d_ws, size_t ws_size,
                              hipStream_t stream) {
  const float* edge_distance  = (const float*)d_in[0];
  const int*   source_element = (const int*)  d_in[1];
  const int*   target_element = (const int*)  d_in[2];
  const float* x_sph   = (const float*)d_in[3];
  const float* edge_sh = (const float*)d_in[4];
  const float* W_dist  = (const float*)d_in[5];
  const float* b_dist  = (const float*)d_in[6];
  const float* src_emb = (const float*)d_in[7];
  const float* tgt_emb = (const float*)d_in[8];
  const float* W_edge  = (const float*)d_in[9];
  const float* b_edge  = (const float*)d_in[10];
  const float* W_g1    = (const float*)d_in[11];
  const float* b_g1    = (const float*)d_in[12];
  const float* W_g2    = (const float*)d_in[13];
  const float* b_g2    = (const float*)d_in[14];
  const float* cg_mid  = (const float*)d_in[15];
  const float* cg_all  = (const float*)d_in[16];
  const float* W_path  = (const float*)d_in[17];
  float* out = (float*)d_out;
  ushort_t* ws = (ushort_t*)d_ws;
  const int E = in_sizes[0];

  hipLaunchKernelGGL(prep_weights_kernel, dim3((WS_TOTAL + 255)/256), dim3(256), 0, stream,
                     W_edge, W_g1, W_g2, ws);

  const int nblk = (E + E_TILE - 1) / E_TILE;
  hipLaunchKernelGGL(edge_block_kernel, dim3(nblk), dim3(THREADS), 0, stream,
                     edge_distance, source_element, target_element, x_sph, edge_sh,
                     W_dist, b_dist, src_emb, tgt_emb, b_edge,
                     b_g1, b_g2, cg_mid, cg_all, W_path, ws, out, E);
}

// Round 4
// 451.267 us; speedup vs baseline: 1.0663x; 1.0663x over previous
//
#include <hip/hip_runtime.h>
#include <math.h>

typedef unsigned short ushort_t;
typedef unsigned short u16x8 __attribute__((ext_vector_type(8)));
typedef unsigned short u16x4 __attribute__((ext_vector_type(4)));
typedef float f32x4 __attribute__((ext_vector_type(4)));

#define THREADS 512
#define E_TILE  64
#define NBASIS  512
#define NBF     128
#define SBD     16
#define MBD     9
#define NTAP    17
#define XE_S    136   // ushort stride (128 + 8 pad), 272B rows (16B-aligned, 4-bank stagger)
#define H_S     40    // ushort stride (32 + 8 pad)

// d_ws layout (ushort bf16)
#define WS_WET   0        // W_edge^T  [n=128][k=128]
#define WS_WG1T  16384    // W_g1^T    [q=32][k=128]
#define WS_WG2T  20480    // W_g2^T    [b*128+n=640][k=32]
#define WS_CGT   40960    // cgT [25][256]: rows 0..15 = cg_all k, rows 16..24 = cg_mid k
#define WS_TOTAL 47360

// LDS offsets (float units)  -- total 12736 floats = 49.75 KB -> 3 blocks/CU
#define OFF_XS   0      // 1024 (dead after P4)
#define OFF_SH   1024   // 1024 (dead after P4)
#define OFF_G    2048   // 64*17 = 1088 (dead after P1)
#define OFF_JLO  3136   // 64 int (dead after P1)
#define OFF_SRC  3200   // 64 int (dead after P1)
#define OFF_TGT  3264   // 64 int (dead after P1)
#define OFF_HS   2048   // aliases G..TGT exactly: 1280 floats = 64*40 ushort (h, written P3)
#define OFF_TPM  3328   // 64*10 = 640
#define OFF_SUM  3968   // 64
#define OFF_XE1  4032   // 4352 floats = 64*136 ushort
#define OFF_XE2  8384   // 4352 floats
#define SMEM_FLOATS 12736

__device__ __forceinline__ float fsigmoid(float x){ return 1.0f/(1.0f + __expf(-x)); }
__device__ __forceinline__ float fsilu(float x){ return x/(1.0f + __expf(-x)); }

__device__ __forceinline__ ushort_t f2bf(float f){
  unsigned int u = __float_as_uint(f);
  u += 0x7FFFu + ((u >> 16) & 1u);
  return (ushort_t)(u >> 16);
}
__device__ __forceinline__ float bf2f(ushort_t h){
  return __uint_as_float(((unsigned int)h) << 16);
}
__device__ __forceinline__ void mfma_bf16(f32x4& d, u16x8 a, u16x8 b){
  // D[m][n] += A[m][k]*B[k][n]; A-frag lane(l): m=l&15,k=(l>>4)*8+j; B-frag lane(l): n=l&15,k=(l>>4)*8+j
  asm volatile("v_mfma_f32_16x16x32_bf16 %0, %1, %2, %0" : "+v"(d) : "v"(a), "v"(b));
}

__global__ void prep_weights_kernel(const float* __restrict__ We,
                                    const float* __restrict__ Wg1,
                                    const float* __restrict__ Wg2,
                                    const float* __restrict__ cgm,
                                    const float* __restrict__ cga,
                                    ushort_t* __restrict__ ws){
  int tid = blockIdx.x * 256 + threadIdx.x;
  if (tid < 16384) {                       // WeT[n][k] = We[k][n]
    int n = tid >> 7, k = tid & 127;
    ws[WS_WET + tid] = f2bf(We[k*128 + n]);
  } else if (tid < 20480) {                // Wg1T[q][k] = Wg1[k][q]
    int r = tid - 16384; int q = r >> 7, k = r & 127;
    ws[tid] = f2bf(Wg1[k*32 + q]);
  } else if (tid < 40960) {                // Wg2T[b*128+n][k] = Wg2[k][b*128+n]
    int r = tid - 20480; int bn = r >> 5, k = r & 31;
    ws[tid] = f2bf(Wg2[k*640 + bn]);
  } else if (tid < WS_TOTAL) {             // cgT[row][col]: col = i*16+j
    int r = tid - WS_CGT; int row = r >> 8, col = r & 255;
    float v = (row < 16) ? cga[col*16 + row] : cgm[col*9 + (row-16)];
    ws[tid] = f2bf(v);
  }
}

__global__ __launch_bounds__(THREADS, 6)
void edge_block_kernel(
    const float* __restrict__ edge_distance,
    const int*   __restrict__ source_element,
    const int*   __restrict__ target_element,
    const float* __restrict__ x_sph,
    const float* __restrict__ edge_sh,
    const float* __restrict__ W_dist,
    const float* __restrict__ b_dist,
    const float* __restrict__ src_emb,
    const float* __restrict__ tgt_emb,
    const float* __restrict__ b_edge,
    const float* __restrict__ b_g1,
    const float* __restrict__ b_g2,
    const float* __restrict__ W_path,
    const ushort_t* __restrict__ wT,
    float* __restrict__ out,
    int E)
{
  __shared__ float smem[SMEM_FLOATS];
  float* xs_s  = smem + OFF_XS;
  float* sh_s  = smem + OFF_SH;
  float* g_s   = smem + OFF_G;
  int*   jlo_s = (int*)(smem + OFF_JLO);
  int*   src_s = (int*)(smem + OFF_SRC);
  int*   tgt_s = (int*)(smem + OFF_TGT);
  float* tpm_s = smem + OFF_TPM;
  float* sum_s = smem + OFF_SUM;
  ushort_t* xe1 = (ushort_t*)(smem + OFF_XE1);
  ushort_t* xe2 = (ushort_t*)(smem + OFF_XE2);
  ushort_t* hS  = (ushort_t*)(smem + OFF_HS);   // aliases g/jlo/src/tgt (dead after P1)

  const int tid  = threadIdx.x;
  const int lane = tid & 63;
  const int wid  = tid >> 6;       // 0..7
  const int l16  = lane & 15;
  const int lq   = lane >> 4;      // 0..3
  const int eb   = blockIdx.x * E_TILE;
  const int ne   = min(E_TILE, E - eb);

  // ---------------- P0: stage inputs ----------------
  for (int idx = tid; idx < E_TILE*SBD; idx += THREADS) {
    int e = idx >> 4;
    bool v = (e < ne);
    int gidx = (eb + e)*SBD + (idx & 15);
    xs_s[idx] = v ? x_sph[gidx]   : 0.0f;
    sh_s[idx] = v ? edge_sh[gidx] : 0.0f;
  }
  if (tid < E_TILE) {
    bool v = (tid < ne);
    int ge = eb + tid;
    src_s[tid] = v ? source_element[ge] : 0;
    tgt_s[tid] = v ? target_element[ge] : 0;
  }
  const float INVD = (float)(NBASIS - 1) / 6.0f;   // 511/6
  for (int idx = tid; idx < E_TILE*NTAP; idx += THREADS) {
    int e = idx / NTAP;
    int t = idx - e*NTAP;
    bool v = (e < ne);
    float d  = v ? edge_distance[eb + e] : 0.0f;
    float jd = d * INVD;
    int jlo  = (int)floorf(jd) - 8;
    int j    = jlo + t;
    float dj = jd - (float)j;
    float g  = (v && j >= 0 && j < NBASIS) ? __expf(-0.5f*dj*dj) : 0.0f;
    g_s[e*NTAP + t] = g;
    if (t == 0) jlo_s[e] = jlo;
  }
  __syncthreads();   // (1)

  // ---------------- P1: x_dist (17 taps) + emb + silu -> xe1 bf16 ------
  {
    const int er = tid >> 5;       // 0..15
    const int cq = tid & 31;       // 0..31
    const int e0 = er << 2;
    const int c0 = cq << 2;
    #pragma unroll 1
    for (int i=0;i<4;i++){
      const int e = e0 + i;
      const float4 bd = *(const float4*)(b_dist + c0);
      float a0=bd.x, a1=bd.y, a2=bd.z, a3=bd.w;
      const int jlo = jlo_s[e];
      #pragma unroll 4
      for (int t=0; t<NTAP; t++){
        float g = g_s[e*NTAP + t];
        int j = jlo + t;
        j = max(0, min(NBASIS-1, j));
        const float4 w = *(const float4*)(W_dist + j*NBF + c0);
        a0 += g*w.x; a1 += g*w.y; a2 += g*w.z; a3 += g*w.w;
      }
      const float4 se = *(const float4*)(src_emb + src_s[e]*NBF + c0);
      const float4 te = *(const float4*)(tgt_emb + tgt_s[e]*NBF + c0);
      u16x4 v;
      v[0] = f2bf(fsilu(a0 + se.x + te.x));
      v[1] = f2bf(fsilu(a1 + se.y + te.y));
      v[2] = f2bf(fsilu(a2 + se.z + te.z));
      v[3] = f2bf(fsilu(a3 + se.w + te.w));
      *(u16x4*)(xe1 + e*XE_S + c0) = v;
    }
  }

  // ------- P4: tensor products, 2 edges x 2 passes, cg bf16 from ws ----
  {
    const int kk = tid & 31;       // lane role: 0..15 = tp_all k, 16..24 = tp_mid k
    const int eg = tid >> 5;
    const ushort_t* cgp = wT + WS_CGT + kk*256;
    #pragma unroll 1
    for (int p=0;p<2;p++){
      const int ea = eg*4 + p*2;
      float acc0 = 0.0f, acc1 = 0.0f;
      if (kk < 25) {
        float sh0[16], sh1[16];
        #pragma unroll
        for (int j=0;j<16;j++){ sh0[j]=sh_s[ea*SBD+j]; sh1[j]=sh_s[(ea+1)*SBD+j]; }
        #pragma unroll 2
        for (int i=0;i<16;i++){
          const u16x8 ca = *(const u16x8*)(cgp + i*16);
          const u16x8 cb = *(const u16x8*)(cgp + i*16 + 8);
          float s0=0.0f, s1=0.0f;
          #pragma unroll
          for (int j=0;j<8;j++){ float c = bf2f(ca[j]); s0 += sh0[j]*c;   s1 += sh1[j]*c; }
          #pragma unroll
          for (int j=0;j<8;j++){ float c = bf2f(cb[j]); s0 += sh0[8+j]*c; s1 += sh1[8+j]*c; }
          acc0 += xs_s[ea*SBD+i]*s0;
          acc1 += xs_s[(ea+1)*SBD+i]*s1;
        }
      }
      if (kk < 16) {
        float t00 = acc0, t01 = acc1;
        float s0v = acc0, s1v = acc1;
        #pragma unroll
        for (int m=1;m<16;m<<=1){ s0v += __shfl_xor(s0v,m); s1v += __shfl_xor(s1v,m); }
        if (kk == 0) {
          sum_s[ea]   = fsigmoid(t00)*s0v;   // silu(t0)+sigmoid(t0)*sum(rest) = sigmoid(t0)*sum(all)
          sum_s[ea+1] = fsigmoid(t01)*s1v;
        }
      } else if (kk < 25) {
        tpm_s[ea*10     + kk-16] = acc0;
        tpm_s[(ea+1)*10 + kk-16] = acc1;
      }
    }
  }
  __syncthreads();   // (2) publishes xe1, tpm, sum

  // ---------------- P2: xe2 = silu(xe1 @ W_edge + b_edge) via MFMA -----
  const int m0 = (wid & 3) * 16;
  const int nb = (wid >> 2) * 64;
  {
    #pragma unroll 1
    for (int t=0;t<4;t++){
      f32x4 acc = (f32x4){0.f,0.f,0.f,0.f};
      #pragma unroll
      for (int kk=0; kk<4; kk++){
        const u16x8 a = *(const u16x8*)(xe1 + (m0 + l16)*XE_S + kk*32 + lq*8);
        const u16x8 b = *(const u16x8*)(wT + WS_WET + (nb + t*16 + l16)*128 + kk*32 + lq*8);
        mfma_bf16(acc, a, b);
      }
      const int n = nb + t*16 + l16;
      const float be = b_edge[n];
      #pragma unroll
      for (int j=0;j<4;j++){
        const int m = m0 + lq*4 + j;
        xe2[m*XE_S + n] = f2bf(fsilu(acc[j] + be));
      }
    }
  }
  __syncthreads();   // (3) publishes xe2

  // ---------------- P3: h = relu(xe2 @ W_g1 + b_g1) via MFMA -----------
  {
    const int n0 = (wid >> 2) * 16;   // 0 or 16
    f32x4 acc3 = (f32x4){0.f,0.f,0.f,0.f};
    #pragma unroll
    for (int kk=0; kk<4; kk++){
      const u16x8 a = *(const u16x8*)(xe2 + (m0 + l16)*XE_S + kk*32 + lq*8);
      const u16x8 b = *(const u16x8*)(wT + WS_WG1T + (n0 + l16)*128 + kk*32 + lq*8);
      mfma_bf16(acc3, a, b);
    }
    const float bg = b_g1[n0 + l16];
    #pragma unroll
    for (int j=0;j<4;j++){
      const int m = m0 + lq*4 + j;
      hS[m*H_S + n0 + l16] = f2bf(fmaxf(acc3[j] + bg, 0.0f));
    }
  }
  __syncthreads();   // (4) publishes h

  // ------- P5+P6: per 16-ch tile t: gate MFMA x5, softmax, store -------
  {
    const int cb = (wid >> 2) * 64;
    const u16x8 ah = *(const u16x8*)(hS + (m0 + l16)*H_S + lq*8);
    #pragma unroll 1
    for (int t=0;t<4;t++){
      const int c = cb + t*16 + l16;
      float sden4[4] = {0.f,0.f,0.f,0.f};
      float z0e4[4];
      #pragma unroll
      for (int b=0;b<5;b++){
        const u16x8 bw = *(const u16x8*)(wT + WS_WG2T + (b*128 + c)*32 + lq*8);
        f32x4 z = (f32x4){0.f,0.f,0.f,0.f};
        mfma_bf16(z, ah, bw);
        const float bg = b_g2[b*128 + c];
        #pragma unroll
        for (int j=0;j<4;j++){
          float ez = __expf(z[j] + bg);
          sden4[j] += ez;
          if (b == 0) z0e4[j] = ez;
        }
      }
      const float wp0 = W_path[c];
      const float wp1 = W_path[128 + c];
      const float wp2 = W_path[256 + c];
      #pragma unroll
      for (int j=0;j<4;j++){
        const int m = m0 + lq*4 + j;
        if (m < ne){
          const float sa = sum_s[m];
          const float g0 = z0e4[j] / sden4[j];
          const float base = bf2f(xe2[m*XE_S + c]) + sa;
          const float s0 = tpm_s[m*10] * wp0;
          const float sg = fsigmoid(s0);
          const float gg = sg * g0;
          float* op = out + (size_t)(eb + m) * (MBD*NBF);
          op[c] = s0*gg + base;
          #pragma unroll
          for (int k=1;k<MBD;k++){
            const float w = (k < 4) ? wp1 : wp2;
            op[k*NBF + c] = tpm_s[m*10 + k]*w*gg + base;
          }
        }
      }
    }
  }
}

extern "C" void kernel_launch(void* const* d_in, const int* in_sizes, int n_in,
                              void* d_out, int out_size, void* d_ws, size_t ws_size,
                              hipStream_t stream) {
  const float* edge_distance  = (const float*)d_in[0];
  const int*   source_element = (const int*)  d_in[1];
  const int*   target_element = (const int*)  d_in[2];
  const float* x_sph   = (const float*)d_in[3];
  const float* edge_sh = (const float*)d_in[4];
  const float* W_dist  = (const float*)d_in[5];
  const float* b_dist  = (const float*)d_in[6];
  const float* src_emb = (const float*)d_in[7];
  const float* tgt_emb = (const float*)d_in[8];
  const float* W_edge  = (const float*)d_in[9];
  const float* b_edge  = (const float*)d_in[10];
  const float* W_g1    = (const float*)d_in[11];
  const float* b_g1    = (const float*)d_in[12];
  const float* W_g2    = (const float*)d_in[13];
  const float* b_g2    = (const float*)d_in[14];
  const float* cg_mid  = (const float*)d_in[15];
  const float* cg_all  = (const float*)d_in[16];
  const float* W_path  = (const float*)d_in[17];
  float* out = (float*)d_out;
  ushort_t* ws = (ushort_t*)d_ws;
  const int E = in_sizes[0];

  hipLaunchKernelGGL(prep_weights_kernel, dim3((WS_TOTAL + 255)/256), dim3(256), 0, stream,
                     W_edge, W_g1, W_g2, cg_mid, cg_all, ws);

  const int nblk = (E + E_TILE - 1) / E_TILE;
  hipLaunchKernelGGL(edge_block_kernel, dim3(nblk), dim3(THREADS), 0, stream,
                     edge_distance, source_element, target_element, x_sph, edge_sh,
                     W_dist, b_dist, src_emb, tgt_emb, b_edge,
                     b_g1, b_g2, W_path, ws, out, E);
}

// Round 5
// 249.310 us; speedup vs baseline: 1.9301x; 1.8101x over previous
//
#include <hip/hip_runtime.h>
#include <math.h>

typedef unsigned short ushort_t;
typedef unsigned short u16x8 __attribute__((ext_vector_type(8)));
typedef unsigned short u16x4 __attribute__((ext_vector_type(4)));
typedef float f32x4 __attribute__((ext_vector_type(4)));

#define THREADS 128
#define ET      16
#define NBASIS  512
#define NBF     128
#define SBD     16
#define MBD     9
#define NTAP    17
#define XE_S    136   // ushort stride; row pitch 272B (16B-aligned)
#define H_S     40    // ushort stride
#define GG_S    136

// d_ws layout (ushort bf16)
#define WS_WET   0        // W_edge^T  [n=128][k=128]
#define WS_WG1T  16384    // W_g1^T    [q=32][k=128]
#define WS_WG2T  20480    // W_g2^T    [b*128+n=640][k=32]
#define WS_CGT   40960    // cgT [25][256]: rows 0..15 = cg_all k, rows 16..24 = cg_mid k
#define WS_TOTAL 47360

// LDS offsets (float units) -- total 3248 floats = 12.7 KB
#define OFF_HS   0      // 320 floats = 16*40 ushort (h; aliases xs, written P3 after xs dead)
#define OFF_XS   0      // 256 (dead after P4)
#define OFF_SH   320    // 256 (dead after P4)
#define OFF_G    576    // 272 (dead after P1)
#define OFF_JLO  848    // 16 int
#define OFF_SRC  864    // 16 int
#define OFF_TGT  880    // 16 int
#define OFF_TPM  896    // 160 (16*10)
#define OFF_SUM  1056   // 16
#define OFF_XE1  1072   // 1088 = 16*136 ushort (xe1; aliased by ggS after P2)
#define OFF_GG   1072   // ggS bf16 [16][136] (written P5)
#define OFF_XE2  2160   // 1088
#define SMEM_FLOATS 3248

__device__ __forceinline__ float fsigmoid(float x){ return 1.0f/(1.0f + __expf(-x)); }
__device__ __forceinline__ float fsilu(float x){ return x/(1.0f + __expf(-x)); }

__device__ __forceinline__ ushort_t f2bf(float f){
  unsigned int u = __float_as_uint(f);
  u += 0x7FFFu + ((u >> 16) & 1u);
  return (ushort_t)(u >> 16);
}
__device__ __forceinline__ float bf2f(ushort_t h){
  return __uint_as_float(((unsigned int)h) << 16);
}
__device__ __forceinline__ void mfma_bf16(f32x4& d, u16x8 a, u16x8 b){
  // D[m][n] += A[m][k]*B[k][n]; A-frag lane(l): m=l&15,k=(l>>4)*8+j; B-frag lane(l): n=l&15,k=(l>>4)*8+j
  asm volatile("v_mfma_f32_16x16x32_bf16 %0, %1, %2, %0" : "+v"(d) : "v"(a), "v"(b));
}

__global__ void prep_weights_kernel(const float* __restrict__ We,
                                    const float* __restrict__ Wg1,
                                    const float* __restrict__ Wg2,
                                    const float* __restrict__ cgm,
                                    const float* __restrict__ cga,
                                    ushort_t* __restrict__ ws){
  int tid = blockIdx.x * 256 + threadIdx.x;
  if (tid < 16384) {                       // WeT[n][k] = We[k][n]
    int n = tid >> 7, k = tid & 127;
    ws[WS_WET + tid] = f2bf(We[k*128 + n]);
  } else if (tid < 20480) {                // Wg1T[q][k] = Wg1[k][q]
    int r = tid - 16384; int q = r >> 7, k = r & 127;
    ws[tid] = f2bf(Wg1[k*32 + q]);
  } else if (tid < 40960) {                // Wg2T[b*128+n][k] = Wg2[k][b*128+n]
    int r = tid - 20480; int bn = r >> 5, k = r & 31;
    ws[tid] = f2bf(Wg2[k*640 + bn]);
  } else if (tid < WS_TOTAL) {             // cgT[row][col]: col = i*16+j
    int r = tid - WS_CGT; int row = r >> 8, col = r & 255;
    float v = (row < 16) ? cga[col*16 + row] : cgm[col*9 + (row-16)];
    ws[tid] = f2bf(v);
  }
}

__global__ __launch_bounds__(THREADS, 4)
void edge_block_kernel(
    const float* __restrict__ edge_distance,
    const int*   __restrict__ source_element,
    const int*   __restrict__ target_element,
    const float* __restrict__ x_sph,
    const float* __restrict__ edge_sh,
    const float* __restrict__ W_dist,
    const float* __restrict__ b_dist,
    const float* __restrict__ src_emb,
    const float* __restrict__ tgt_emb,
    const float* __restrict__ b_edge,
    const float* __restrict__ b_g1,
    const float* __restrict__ b_g2,
    const float* __restrict__ W_path,
    const ushort_t* __restrict__ wT,
    float* __restrict__ out,
    int E)
{
  __shared__ float smem[SMEM_FLOATS];
  float* xs_s  = smem + OFF_XS;
  float* sh_s  = smem + OFF_SH;
  float* g_s   = smem + OFF_G;
  int*   jlo_s = (int*)(smem + OFF_JLO);
  int*   src_s = (int*)(smem + OFF_SRC);
  int*   tgt_s = (int*)(smem + OFF_TGT);
  float* tpm_s = smem + OFF_TPM;
  float* sum_s = smem + OFF_SUM;
  ushort_t* xe1 = (ushort_t*)(smem + OFF_XE1);
  ushort_t* xe2 = (ushort_t*)(smem + OFF_XE2);
  ushort_t* hS  = (ushort_t*)(smem + OFF_HS);   // aliases xs (dead after P4)
  ushort_t* ggS = (ushort_t*)(smem + OFF_GG);   // aliases xe1 (dead after P2)

  const int tid  = threadIdx.x;
  const int lane = tid & 63;
  const int w    = tid >> 6;       // 0..1
  const int l16  = lane & 15;
  const int lq   = lane >> 4;      // 0..3
  const int eb   = blockIdx.x * ET;
  const int ne   = min(ET, E - eb);

  // ---------------- P0: stage inputs ----------------
  for (int idx = tid; idx < ET*SBD; idx += THREADS) {
    int e = idx >> 4;
    bool v = (e < ne);
    int gidx = (eb + e)*SBD + (idx & 15);
    xs_s[idx] = v ? x_sph[gidx]   : 0.0f;
    sh_s[idx] = v ? edge_sh[gidx] : 0.0f;
  }
  if (tid < ET) {
    bool v = (tid < ne);
    int ge = eb + min(tid, ne-1);
    src_s[tid] = v ? source_element[ge] : 0;
    tgt_s[tid] = v ? target_element[ge] : 0;
  }
  const float INVD = (float)(NBASIS - 1) / 6.0f;   // 511/6
  for (int idx = tid; idx < ET*NTAP; idx += THREADS) {
    int e = idx / NTAP;
    int t = idx - e*NTAP;
    bool v = (e < ne);
    float d  = v ? edge_distance[eb + e] : 0.0f;
    float jd = d * INVD;
    int jlo  = (int)floorf(jd) - 8;
    int j    = jlo + t;
    float dj = jd - (float)j;
    float g  = (v && j >= 0 && j < NBASIS) ? __expf(-0.5f*dj*dj) : 0.0f;
    g_s[e*NTAP + t] = g;
    if (t == 0) jlo_s[e] = jlo;
  }
  __syncthreads();   // (1)

  // ---------------- P1: x_dist (17 taps) + emb + silu -> xe1 bf16 ------
  {
    const int er = tid >> 5;       // 0..3  -> 4 edges each
    const int cq = tid & 31;       // 0..31 -> 4 channels each
    const int c0 = cq << 2;
    #pragma unroll 1
    for (int i=0;i<4;i++){
      const int e = er*4 + i;
      const float4 bd = *(const float4*)(b_dist + c0);
      float a0=bd.x, a1=bd.y, a2=bd.z, a3=bd.w;
      const int jlo = jlo_s[e];
      #pragma unroll 4
      for (int t=0; t<NTAP; t++){
        float g = g_s[e*NTAP + t];
        int j = jlo + t;
        j = max(0, min(NBASIS-1, j));
        const float4 wv = *(const float4*)(W_dist + j*NBF + c0);
        a0 += g*wv.x; a1 += g*wv.y; a2 += g*wv.z; a3 += g*wv.w;
      }
      const float4 se = *(const float4*)(src_emb + src_s[e]*NBF + c0);
      const float4 te = *(const float4*)(tgt_emb + tgt_s[e]*NBF + c0);
      u16x4 v;
      v[0] = f2bf(fsilu(a0 + se.x + te.x));
      v[1] = f2bf(fsilu(a1 + se.y + te.y));
      v[2] = f2bf(fsilu(a2 + se.z + te.z));
      v[3] = f2bf(fsilu(a3 + se.w + te.w));
      *(u16x4*)(xe1 + e*XE_S + c0) = v;
    }
  }

  // ------- P4: tensor products, 4 edges x 2 passes, cg bf16 from ws ----
  {
    const int kk = tid & 31;       // 0..15 = tp_all k, 16..24 = tp_mid k
    const int eg = tid >> 5;       // 0..3
    const ushort_t* cgp = wT + WS_CGT + kk*256;
    #pragma unroll 1
    for (int p=0;p<2;p++){
      const int ea = eg*4 + p*2;
      float acc0 = 0.0f, acc1 = 0.0f;
      if (kk < 25) {
        float sh0[16], sh1[16];
        #pragma unroll
        for (int j=0;j<16;j++){ sh0[j]=sh_s[ea*SBD+j]; sh1[j]=sh_s[(ea+1)*SBD+j]; }
        #pragma unroll 2
        for (int i=0;i<16;i++){
          const u16x8 ca = *(const u16x8*)(cgp + i*16);
          const u16x8 cb = *(const u16x8*)(cgp + i*16 + 8);
          float s0=0.0f, s1=0.0f;
          #pragma unroll
          for (int j=0;j<8;j++){ float c = bf2f(ca[j]); s0 += sh0[j]*c;   s1 += sh1[j]*c; }
          #pragma unroll
          for (int j=0;j<8;j++){ float c = bf2f(cb[j]); s0 += sh0[8+j]*c; s1 += sh1[8+j]*c; }
          acc0 += xs_s[ea*SBD+i]*s0;
          acc1 += xs_s[(ea+1)*SBD+i]*s1;
        }
      }
      if (kk < 16) {
        float t00 = acc0, t01 = acc1;
        float s0v = acc0, s1v = acc1;
        #pragma unroll
        for (int m=1;m<16;m<<=1){ s0v += __shfl_xor(s0v,m); s1v += __shfl_xor(s1v,m); }
        if (kk == 0) {
          sum_s[ea]   = fsigmoid(t00)*s0v;   // silu(t0)+sigmoid(t0)*sum(rest)
          sum_s[ea+1] = fsigmoid(t01)*s1v;
        }
      } else if (kk < 25) {
        tpm_s[ea*10     + kk-16] = acc0;
        tpm_s[(ea+1)*10 + kk-16] = acc1;
      }
    }
  }
  __syncthreads();   // (2) publishes xe1, tpm, sum

  // ---------------- P2: xe2 = silu(xe1 @ W_edge + b_edge), MFMA --------
  {
    const int nb = w * 64;
    u16x8 af[4];
    #pragma unroll
    for (int kk=0; kk<4; kk++)
      af[kk] = *(const u16x8*)(xe1 + l16*XE_S + kk*32 + lq*8);
    #pragma unroll 1
    for (int t=0;t<4;t++){
      f32x4 acc = (f32x4){0.f,0.f,0.f,0.f};
      #pragma unroll
      for (int kk=0; kk<4; kk++){
        const u16x8 b = *(const u16x8*)(wT + WS_WET + (nb + t*16 + l16)*128 + kk*32 + lq*8);
        mfma_bf16(acc, af[kk], b);
      }
      const int n = nb + t*16 + l16;
      const float be = b_edge[n];
      #pragma unroll
      for (int j=0;j<4;j++){
        const int m = lq*4 + j;
        xe2[m*XE_S + n] = f2bf(fsilu(acc[j] + be));
      }
    }
  }
  __syncthreads();   // (3) publishes xe2 (xe1 now dead)

  // ---------------- P3: h = relu(xe2 @ W_g1 + b_g1), MFMA --------------
  {
    const int n0 = w * 16;
    f32x4 acc3 = (f32x4){0.f,0.f,0.f,0.f};
    #pragma unroll
    for (int kk=0; kk<4; kk++){
      const u16x8 a = *(const u16x8*)(xe2 + l16*XE_S + kk*32 + lq*8);
      const u16x8 b = *(const u16x8*)(wT + WS_WG1T + (n0 + l16)*128 + kk*32 + lq*8);
      mfma_bf16(acc3, a, b);
    }
    const float bg = b_g1[n0 + l16];
    #pragma unroll
    for (int j=0;j<4;j++){
      const int m = lq*4 + j;
      hS[m*H_S + n0 + l16] = f2bf(fmaxf(acc3[j] + bg, 0.0f));
    }
  }
  __syncthreads();   // (4) publishes h

  // ------- P5: gate branch-0 via MFMA x5 per 16-ch tile -> ggS bf16 ----
  {
    const int cb = w * 64;
    const u16x8 ah = *(const u16x8*)(hS + l16*H_S + lq*8);
    #pragma unroll 1
    for (int t=0;t<4;t++){
      const int c = cb + t*16 + l16;
      float sden4[4] = {0.f,0.f,0.f,0.f};
      float z0e4[4];
      #pragma unroll
      for (int b=0;b<5;b++){
        const u16x8 bw = *(const u16x8*)(wT + WS_WG2T + (b*128 + c)*32 + lq*8);
        f32x4 z = (f32x4){0.f,0.f,0.f,0.f};
        mfma_bf16(z, ah, bw);
        const float bg = b_g2[b*128 + c];
        #pragma unroll
        for (int j=0;j<4;j++){
          float ez = __expf(z[j] + bg);
          sden4[j] += ez;
          if (b == 0) z0e4[j] = ez;
        }
      }
      #pragma unroll
      for (int j=0;j<4;j++){
        const int m = lq*4 + j;
        ggS[m*GG_S + c] = f2bf(z0e4[j] / sden4[j]);   // softmax branch-0 gate
      }
    }
  }
  __syncthreads();   // (5) publishes ggS

  // ------- P6: assemble + float4 stores, thread owns (4 m) x (4 c) -----
  {
    const int c0 = (tid & 31) << 2;
    const int mg = tid >> 5;           // 0..3
    const float4 wp0 = *(const float4*)(W_path + c0);
    const float4 wp1 = *(const float4*)(W_path + 128 + c0);
    const float4 wp2 = *(const float4*)(W_path + 256 + c0);
    #pragma unroll
    for (int mm=0; mm<4; mm++){
      const int m = mg*4 + mm;
      if (m < ne){
        const float sa = sum_s[m];
        const u16x4 xv = *(const u16x4*)(xe2 + m*XE_S + c0);
        const u16x4 gv = *(const u16x4*)(ggS + m*GG_S + c0);
        float tpmv[9];
        #pragma unroll
        for (int k=0;k<MBD;k++) tpmv[k] = tpm_s[m*10 + k];
        float base[4], gg[4], s0[4];
        #pragma unroll
        for (int j=0;j<4;j++){
          base[j] = bf2f(xv[j]) + sa;
          float wpj = (j==0)?wp0.x:(j==1)?wp0.y:(j==2)?wp0.z:wp0.w;
          s0[j] = tpmv[0] * wpj;
          gg[j] = fsigmoid(s0[j]) * bf2f(gv[j]);
        }
        float* op = out + (size_t)(eb + m) * (MBD*NBF) + c0;
        float4 o;
        o.x = s0[0]*gg[0] + base[0];
        o.y = s0[1]*gg[1] + base[1];
        o.z = s0[2]*gg[2] + base[2];
        o.w = s0[3]*gg[3] + base[3];
        *(float4*)op = o;
        #pragma unroll
        for (int k=1;k<MBD;k++){
          const float4 wv = (k < 4) ? wp1 : wp2;
          o.x = tpmv[k]*wv.x*gg[0] + base[0];
          o.y = tpmv[k]*wv.y*gg[1] + base[1];
          o.z = tpmv[k]*wv.z*gg[2] + base[2];
          o.w = tpmv[k]*wv.w*gg[3] + base[3];
          *(float4*)(op + k*NBF) = o;
        }
      }
    }
  }
}

extern "C" void kernel_launch(void* const* d_in, const int* in_sizes, int n_in,
                              void* d_out, int out_size, void* d_ws, size_t ws_size,
                              hipStream_t stream) {
  const float* edge_distance  = (const float*)d_in[0];
  const int*   source_element = (const int*)  d_in[1];
  const int*   target_element = (const int*)  d_in[2];
  const float* x_sph   = (const float*)d_in[3];
  const float* edge_sh = (const float*)d_in[4];
  const float* W_dist  = (const float*)d_in[5];
  const float* b_dist  = (const float*)d_in[6];
  const float* src_emb = (const float*)d_in[7];
  const float* tgt_emb = (const float*)d_in[8];
  const float* W_edge  = (const float*)d_in[9];
  const float* b_edge  = (const float*)d_in[10];
  const float* W_g1    = (const float*)d_in[11];
  const float* b_g1    = (const float*)d_in[12];
  const float* W_g2    = (const float*)d_in[13];
  const float* b_g2    = (const float*)d_in[14];
  const float* cg_mid  = (const float*)d_in[15];
  const float* cg_all  = (const float*)d_in[16];
  const float* W_path  = (const float*)d_in[17];
  float* out = (float*)d_out;
  ushort_t* ws = (ushort_t*)d_ws;
  const int E = in_sizes[0];

  hipLaunchKernelGGL(prep_weights_kernel, dim3((WS_TOTAL + 255)/256), dim3(256), 0, stream,
                     W_edge, W_g1, W_g2, cg_mid, cg_all, ws);

  const int nblk = (E + ET - 1) / ET;
  hipLaunchKernelGGL(edge_block_kernel, dim3(nblk), dim3(THREADS), 0, stream,
                     edge_distance, source_element, target_element, x_sph, edge_sh,
                     W_dist, b_dist, src_emb, tgt_emb, b_edge,
                     b_g1, b_g2, W_path, ws, out, E);
}